// Round 5
// baseline (496.474 us; speedup 1.0000x reference)
//
#include <hip/hip_runtime.h>
#include <hip/hip_bf16.h>

// Problem constants
#define BATCH   4
#define SEQ     2048
#define DMODEL  1024
#define NHEADS  16
#define DHEAD   64
#define BT      (BATCH*SEQ)   // 8192 tokens

typedef unsigned short u16;
typedef __bf16 bf16x8 __attribute__((ext_vector_type(8)));
typedef float  f32x4  __attribute__((ext_vector_type(4)));
typedef u16    u16x8  __attribute__((ext_vector_type(8)));

#define MFMA16(a,b,c) __builtin_amdgcn_mfma_f32_16x16x32_bf16((a),(b),(c),0,0,0)

__device__ __forceinline__ u16 f2b(float f) {
  return __builtin_bit_cast(u16, (__bf16)f);
}

__device__ __forceinline__ void gload_lds16(const u16* g, u16* l) {
  __builtin_amdgcn_global_load_lds(
      (const __attribute__((address_space(1))) void*)g,
      (__attribute__((address_space(3))) void*)l, 16, 0, 0);
}

// ---------------- elementwise f32 -> bf16 ----------------
__global__ __launch_bounds__(256) void cvt_bf16_kernel(
    const float* __restrict__ in, u16* __restrict__ out, int n8) {
  int i = blockIdx.x * 256 + threadIdx.x;
  if (i >= n8) return;
  const float4* p = (const float4*)(in + (long)i * 8);
  float4 a = p[0], b = p[1];
  u16x8 o;
  o[0]=f2b(a.x); o[1]=f2b(a.y); o[2]=f2b(a.z); o[3]=f2b(a.w);
  o[4]=f2b(b.x); o[5]=f2b(b.y); o[6]=f2b(b.z); o[7]=f2b(b.w);
  *(u16x8*)(out + (long)i * 8) = o;
}

// ---------------- transpose + cvt: W[K][N] f32 -> Wt[N][K] bf16 ----------------
__global__ __launch_bounds__(256) void transpose_cvt_kernel(
    const float* __restrict__ W, u16* __restrict__ Wt, int K, int N) {
  __shared__ float tile[32][33];   // +1 pad: no bank conflicts
  int tx = threadIdx.x & 31, ty = threadIdx.x >> 5; // 32x8
  int bx = blockIdx.x, by = blockIdx.y;
  #pragma unroll
  for (int r = 0; r < 32; r += 8)
    tile[ty + r][tx] = W[(long)(by * 32 + ty + r) * N + bx * 32 + tx];
  __syncthreads();
  #pragma unroll
  for (int r = 0; r < 32; r += 8)
    Wt[(long)(bx * 32 + ty + r) * K + by * 32 + tx] = f2b(tile[tx][ty + r]);
}

// ---------------- 128x128 bf16 GEMM, B given transposed [N][K] ----------------
// MODE 0: C[M][N] fp32 plain store.
// MODE 1: qkv scatter epilogue: col c = s*1024 + h*64 + d
//   s=0 -> Qb[bh][t][d] * 0.125   s=1 -> Kb[bh][t][d]   s=2 -> Vt[bh][d][t]
template<int MODE>
__global__ __launch_bounds__(256) void gemm_bt_kernel(
    const u16* __restrict__ A, const u16* __restrict__ Bt,
    float* __restrict__ C,
    u16* __restrict__ Qb, u16* __restrict__ Kb, u16* __restrict__ Vt,
    int M, int N, int K) {
  __shared__ u16 lA[128 * 32];
  __shared__ u16 lB[128 * 32];
  const int tid = threadIdx.x;
  const int l = tid & 63, w = tid >> 6;
  const int g = l >> 4, c16 = l & 15;
  const int bn = blockIdx.x, bm = blockIdx.y;
  const int wm = w >> 1, wn = w & 1;
  // staging: each thread stages 16B per issue; 2 issues per tile per operand
  const int srow = tid >> 2;
  const int scol = (tid & 3) << 3;
  const u16* Ab0 = A  + (long)(bm * 128 + srow)      * K + scol;
  const u16* Ab1 = A  + (long)(bm * 128 + 64 + srow) * K + scol;
  const u16* Bb0 = Bt + (long)(bn * 128 + srow)      * K + scol;
  const u16* Bb1 = Bt + (long)(bn * 128 + 64 + srow) * K + scol;
  u16* lA0 = &lA[srow * 32 + scol];
  u16* lA1 = &lA[(64 + srow) * 32 + scol];
  u16* lB0 = &lB[srow * 32 + scol];
  u16* lB1 = &lB[(64 + srow) * 32 + scol];

  f32x4 acc[4][4];
  #pragma unroll
  for (int i = 0; i < 4; ++i)
    #pragma unroll
    for (int j = 0; j < 4; ++j)
      #pragma unroll
      for (int e = 0; e < 4; ++e) acc[i][j][e] = 0.f;

  for (int k0 = 0; k0 < K; k0 += 32) {
    gload_lds16(Ab0 + k0, lA0);
    gload_lds16(Ab1 + k0, lA1);
    gload_lds16(Bb0 + k0, lB0);
    gload_lds16(Bb1 + k0, lB1);
    __syncthreads();   // drains vmcnt(0), LDS tile ready
    bf16x8 af[4];
    #pragma unroll
    for (int mf = 0; mf < 4; ++mf)
      af[mf] = *(const bf16x8*)&lA[(wm * 64 + mf * 16 + c16) * 32 + g * 8];
    #pragma unroll
    for (int nf = 0; nf < 4; ++nf) {
      bf16x8 bfr = *(const bf16x8*)&lB[(wn * 64 + nf * 16 + c16) * 32 + g * 8];
      #pragma unroll
      for (int mf = 0; mf < 4; ++mf)
        acc[mf][nf] = MFMA16(af[mf], bfr, acc[mf][nf]);
    }
    __syncthreads();   // protect LDS before next stage
  }

  #pragma unroll
  for (int mf = 0; mf < 4; ++mf) {
    const int trow_base = bm * 128 + wm * 64 + mf * 16 + g * 4;
    #pragma unroll
    for (int nf = 0; nf < 4; ++nf) {
      const int col = bn * 128 + wn * 64 + nf * 16 + c16;
      #pragma unroll
      for (int r = 0; r < 4; ++r) {
        const float v = acc[mf][nf][r];
        const int trow = trow_base + r;
        if constexpr (MODE == 0) {
          C[(long)trow * N + col] = v;
        } else {
          const int s = col >> 10;
          const int rem = col & 1023;
          const int h = rem >> 6, d = rem & 63;
          const int b = trow >> 11, tt = trow & 2047;
          const int bh = b * NHEADS + h;
          if (s == 0)      Qb[((long)bh * SEQ + tt) * DHEAD + d] = f2b(v * 0.125f);
          else if (s == 1) Kb[((long)bh * SEQ + tt) * DHEAD + d] = f2b(v);
          else             Vt[((long)bh * DHEAD + d) * SEQ + tt] = f2b(v);
        }
      }
    }
  }
}

// ---------------- causal flash attention ----------------
// grid (B*H, T/64); 256 threads = 4 waves, wave wid owns 16 q-rows.
// Q pre-scaled by 1/8. K [bh][t][64], Vt [bh][64][t], out Ob [b*T+t][h*64+d] bf16.
__global__ __launch_bounds__(256) void attn_kernel(
    const u16* __restrict__ Qb, const u16* __restrict__ Kb,
    const u16* __restrict__ Vt, u16* __restrict__ Ob) {
  __shared__ u16 lP[4][16 * 64];   // per-wave P buffer, XOR-swizzled
  const int tid = threadIdx.x;
  const int l = tid & 63, wid = tid >> 6;
  const int g = l >> 4, c16 = l & 15;
  const int bh = blockIdx.x;
  const int b = bh >> 4, h = bh & 15;
  const int qb0 = blockIdx.y * 64;
  const int qrow = qb0 + wid * 16;

  // Q fragments (A-operand): row = qrow + c16, k-slice = ks*32 + 8g
  const u16* Qrow = &Qb[((long)bh * SEQ + qrow + c16) * DHEAD];
  bf16x8 aq0 = *(const bf16x8*)&Qrow[8 * g];
  bf16x8 aq1 = *(const bf16x8*)&Qrow[32 + 8 * g];

  f32x4 o[4];
  #pragma unroll
  for (int i = 0; i < 4; ++i)
    #pragma unroll
    for (int e = 0; e < 4; ++e) o[i][e] = 0.f;
  float m0[4], sumv[4];
  #pragma unroll
  for (int r = 0; r < 4; ++r) { m0[r] = -__builtin_inff(); sumv[r] = 0.f; }

  const int ntiles = blockIdx.y + 1;   // keys 0 .. qb0+63
  for (int t = 0; t < ntiles; ++t) {
    const int kv = t * 64;
    // ---- S = Q K^T (per wave: 16 x 64) ----
    f32x4 s4[4];
    #pragma unroll
    for (int nf = 0; nf < 4; ++nf) {
      #pragma unroll
      for (int e = 0; e < 4; ++e) s4[nf][e] = 0.f;
      const u16* Krow = &Kb[((long)bh * SEQ + kv + nf * 16 + c16) * DHEAD];
      bf16x8 bk0 = *(const bf16x8*)&Krow[8 * g];
      bf16x8 bk1 = *(const bf16x8*)&Krow[32 + 8 * g];
      s4[nf] = MFMA16(aq0, bk0, s4[nf]);
      s4[nf] = MFMA16(aq1, bk1, s4[nf]);
    }
    // ---- causal mask + per-row max (rows 4g+r, cols c16+16nf) ----
    float rmax[4];
    #pragma unroll
    for (int r = 0; r < 4; ++r) {
      const int q = qrow + 4 * g + r;
      float mx = -__builtin_inff();
      #pragma unroll
      for (int nf = 0; nf < 4; ++nf) {
        const int j = kv + nf * 16 + c16;
        float v = (j <= q) ? s4[nf][r] : -__builtin_inff();
        s4[nf][r] = v;
        mx = fmaxf(mx, v);
      }
      rmax[r] = mx;
    }
    #pragma unroll
    for (int mk = 1; mk < 16; mk <<= 1)
      #pragma unroll
      for (int r = 0; r < 4; ++r)
        rmax[r] = fmaxf(rmax[r], __shfl_xor(rmax[r], mk, 64));
    // ---- online softmax ----
    float fs[4], psum[4];
    #pragma unroll
    for (int r = 0; r < 4; ++r) {
      const float mnew = fmaxf(m0[r], rmax[r]);
      fs[r] = exp2f((m0[r] - mnew) * 1.44269504f);
      m0[r] = mnew;
      float ps = 0.f;
      #pragma unroll
      for (int nf = 0; nf < 4; ++nf) {
        const float p = exp2f((s4[nf][r] - mnew) * 1.44269504f);
        s4[nf][r] = p;
        ps += p;
      }
      psum[r] = ps;
    }
    #pragma unroll
    for (int mk = 1; mk < 16; mk <<= 1)
      #pragma unroll
      for (int r = 0; r < 4; ++r)
        psum[r] += __shfl_xor(psum[r], mk, 64);
    #pragma unroll
    for (int r = 0; r < 4; ++r) sumv[r] = sumv[r] * fs[r] + psum[r];
    #pragma unroll
    for (int df = 0; df < 4; ++df)
      #pragma unroll
      for (int r = 0; r < 4; ++r) o[df][r] *= fs[r];
    // ---- P -> LDS (bf16, XOR swizzle byte ^= (row&7)<<4) ----
    #pragma unroll
    for (int r = 0; r < 4; ++r) {
      const int row = 4 * g + r;
      #pragma unroll
      for (int nf = 0; nf < 4; ++nf) {
        const int off = row * 128 + ((2 * (c16 + 16 * nf)) ^ ((row & 7) << 4));
        *(u16*)((char*)&lP[wid][0] + off) = f2b(s4[nf][r]);
      }
    }
    asm volatile("" ::: "memory");   // order LDS writes before reads (same wave)
    // ---- P A-fragments: row = c16, k-slice = ks*32 + 8g ----
    bf16x8 ap0, ap1;
    {
      const int row = c16;
      const char* base = (const char*)&lP[wid][0] + row * 128;
      ap0 = *(const bf16x8*)(base + ((g * 16) ^ ((row & 7) << 4)));
      ap1 = *(const bf16x8*)(base + ((64 + g * 16) ^ ((row & 7) << 4)));
    }
    asm volatile("" ::: "memory");   // order LDS reads before next tile's writes
    // ---- O += P V ----
    #pragma unroll
    for (int df = 0; df < 4; ++df) {
      const u16* Vrow = &Vt[((long)bh * DHEAD + df * 16 + c16) * SEQ + kv];
      bf16x8 bv0 = *(const bf16x8*)&Vrow[8 * g];
      bf16x8 bv1 = *(const bf16x8*)&Vrow[32 + 8 * g];
      o[df] = MFMA16(ap0, bv0, o[df]);
      o[df] = MFMA16(ap1, bv1, o[df]);
    }
  }
  // ---- normalize + store [b*T+t][h*64 + d] bf16 ----
  #pragma unroll
  for (int df = 0; df < 4; ++df)
    #pragma unroll
    for (int r = 0; r < 4; ++r) {
      const float v = o[df][r] / sumv[r];
      const int trow = qrow + 4 * g + r;
      Ob[((long)b * SEQ + trow) * DMODEL + h * DHEAD + df * 16 + c16] = f2b(v);
    }
}

extern "C" void kernel_launch(void* const* d_in, const int* in_sizes, int n_in,
                              void* d_out, int out_size, void* d_ws, size_t ws_size,
                              hipStream_t stream) {
  const float* x    = (const float*)d_in[0];
  // d_in[1] = mask (causal tril) — implemented implicitly
  const float* Wqkv = (const float*)d_in[2];
  const float* Wout = (const float*)d_in[3];
  float* out = (float*)d_out;
  char* ws = (char*)d_ws;
  // ws layout (bytes)
  u16* Xb  = (u16*)(ws + 0);          // 8192x1024 bf16      16,777,216
  u16* Wt1 = (u16*)(ws + 16777216);   // 3072x1024 bf16       6,291,456
  u16* Wt2 = (u16*)(ws + 23068672);   // 1024x1024 bf16       2,097,152
  u16* Qb  = (u16*)(ws + 25165824);   // [64][2048][64] bf16 16,777,216
  u16* Kb  = (u16*)(ws + 41943040);   // [64][2048][64] bf16 16,777,216
  u16* Vt  = (u16*)(ws + 58720256);   // [64][64][2048] bf16 16,777,216
  u16* Ob  = (u16*)(ws + 75497472);   // 8192x1024 bf16      16,777,216

  cvt_bf16_kernel<<<4096, 256, 0, stream>>>(x, Xb, BT * DMODEL / 8);
  transpose_cvt_kernel<<<dim3(96, 32), 256, 0, stream>>>(Wqkv, Wt1, DMODEL, 3 * DMODEL);
  transpose_cvt_kernel<<<dim3(32, 32), 256, 0, stream>>>(Wout, Wt2, DMODEL, DMODEL);
  gemm_bt_kernel<1><<<dim3(24, 64), 256, 0, stream>>>(
      Xb, Wt1, nullptr, Qb, Kb, Vt, BT, 3 * DMODEL, DMODEL);
  attn_kernel<<<dim3(64, 32), 256, 0, stream>>>(Qb, Kb, Vt, Ob);
  gemm_bt_kernel<0><<<dim3(8, 64), 256, 0, stream>>>(
      Ob, Wt2, out, nullptr, nullptr, nullptr, BT, DMODEL, DMODEL);
}